// Round 1
// baseline (194.442 us; speedup 1.0000x reference)
//
#include <hip/hip_runtime.h>
#include <cstdint>
#include <cstddef>

#define H 512
#define SEQ 128

typedef __bf16 v8bf __attribute__((ext_vector_type(8)));
typedef float v4f __attribute__((ext_vector_type(4)));

__device__ __forceinline__ unsigned short f2bf(float f) {
    unsigned int u = __float_as_uint(f);
    u = (u + 0x7FFFu + ((u >> 16) & 1u)) >> 16;
    return (unsigned short)u;
}
__device__ __forceinline__ float bf2f(unsigned short h) {
    return __uint_as_float(((unsigned int)h) << 16);
}
__device__ __forceinline__ v8bf load_bf8(const unsigned short* p) {
    return *reinterpret_cast<const v8bf*>(p);
}
__device__ __forceinline__ float fast_tanh(float v) {
    float e = __expf(2.f * v);
    return 1.f - 2.f * __builtin_amdgcn_rcpf(e + 1.f);
}
__device__ __forceinline__ float fast_sigmoid(float v) {
    return __builtin_amdgcn_rcpf(1.f + __expf(-v));
}

// Swizzled B layout: frag[((c*16 + ks)*64 + lane)*8 + j] = W[g][k]
//   g = c*16 + (lane&15),  k = ks*32 + (lane>>4)*8 + j
// One wave's B-fragment load for (c,ks) = 64 lanes x 16B contiguous (1 KB).

// ---------------------------------------------------------------------------
// prep: build swizzled WyS (Wl[:, :512]), WiS (Wl[:, 512:]), WaS (Wa1^T)
// ---------------------------------------------------------------------------
__global__ __launch_bounds__(256) void prep_kernel(
        const float* __restrict__ Wa1, const float* __restrict__ Wl,
        unsigned short* __restrict__ WyS, unsigned short* __restrict__ WiS,
        unsigned short* __restrict__ WaS) {
    int tg = blockIdx.x * 256 + threadIdx.x;   // 0..98303
    int mat = tg >> 15;
    int idx = tg & 32767;
    int lane = idx & 63;
    int ks = (idx >> 6) & 15;
    int c = idx >> 10;
    int g = c * 16 + (lane & 15);
    int hb = ks * 32 + ((lane >> 4) << 3);
    unsigned short o[8];
    unsigned short* dst;
    if (mat == 0) {
        const float* s = Wl + (size_t)g * 1024 + hb;
#pragma unroll
        for (int j = 0; j < 8; ++j) o[j] = f2bf(s[j]);
        dst = WyS + (size_t)idx * 8;
    } else if (mat == 1) {
        const float* s = Wl + (size_t)g * 1024 + 512 + hb;
#pragma unroll
        for (int j = 0; j < 8; ++j) o[j] = f2bf(s[j]);
        dst = WiS + (size_t)idx * 8;
    } else {
#pragma unroll
        for (int j = 0; j < 8; ++j) o[j] = f2bf(Wa1[(size_t)(hb + j) * H + g]);
        dst = WaS + (size_t)idx * 8;
    }
    *reinterpret_cast<ushort4*>(dst)     = *reinterpret_cast<ushort4*>(&o[0]);
    *reinterpret_cast<ushort4*>(dst + 4) = *reinterpret_cast<ushort4*>(&o[4]);
}

// ---------------------------------------------------------------------------
// attn_pool: one block per (b, s<127).  wave = 32 rows x 128 cols, acc 2x8.
// ---------------------------------------------------------------------------
__global__ __launch_bounds__(256, 3) void attn_pool_kernel(
        const float* __restrict__ x, const unsigned short* __restrict__ WaS,
        const float* __restrict__ ba1, const float* __restrict__ wa2,
        float* __restrict__ ixf, unsigned short* __restrict__ ixb) {
    __shared__ __align__(16) unsigned short Xb[32][520];
    __shared__ float attn[32];
    __shared__ float scpart[4][32];

    int bid = blockIdx.x;
    int b = bid / 127, s = bid % 127;
    int t = threadIdx.x;

    const float4* x4 = reinterpret_cast<const float4*>(x + (size_t)(b * SEQ + s) * 32 * H);
#pragma unroll
    for (int i = 0; i < 16; ++i) {
        int idx4 = t + i * 256;
        float4 v = x4[idx4];
        int e = idx4 * 4, m = e >> 9, h = e & 511;
        ushort4 o;
        o.x = f2bf(v.x); o.y = f2bf(v.y); o.z = f2bf(v.z); o.w = f2bf(v.w);
        *reinterpret_cast<ushort4*>(&Xb[m][h]) = o;
    }
    __syncthreads();

    int w = t >> 6, lane = t & 63, q = lane >> 4, c16 = lane & 15;

    v4f acc[2][8];
#pragma unroll
    for (int mi = 0; mi < 2; ++mi)
#pragma unroll
        for (int ci = 0; ci < 8; ++ci) acc[mi][ci] = (v4f){0.f, 0.f, 0.f, 0.f};

    const unsigned short* Bb = WaS + (size_t)(w * 8 * 16) * 512 + lane * 8;

#pragma unroll
    for (int ks = 0; ks < 16; ++ks) {
        v8bf a0 = load_bf8(&Xb[c16][ks * 32 + q * 8]);
        v8bf a1 = load_bf8(&Xb[16 + c16][ks * 32 + q * 8]);
#pragma unroll
        for (int ci = 0; ci < 8; ++ci) {
            v8bf bb = load_bf8(Bb + (size_t)(ci * 16 + ks) * 512);
            acc[0][ci] = __builtin_amdgcn_mfma_f32_16x16x32_bf16(a0, bb, acc[0][ci], 0, 0, 0);
            acc[1][ci] = __builtin_amdgcn_mfma_f32_16x16x32_bf16(a1, bb, acc[1][ci], 0, 0, 0);
        }
    }

    float sr[2][4] = {{0.f, 0.f, 0.f, 0.f}, {0.f, 0.f, 0.f, 0.f}};
#pragma unroll
    for (int ci = 0; ci < 8; ++ci) {
        int g = (w * 8 + ci) * 16 + c16;
        float w2 = wa2[g];
        float bv = ba1[g];
#pragma unroll
        for (int mi = 0; mi < 2; ++mi)
#pragma unroll
            for (int i = 0; i < 4; ++i)
                sr[mi][i] += w2 * fast_tanh(acc[mi][ci][i] + bv);
    }
#pragma unroll
    for (int off = 1; off < 16; off <<= 1) {
#pragma unroll
        for (int mi = 0; mi < 2; ++mi)
#pragma unroll
            for (int i = 0; i < 4; ++i) sr[mi][i] += __shfl_xor(sr[mi][i], off);
    }
    if (c16 == 0) {
#pragma unroll
        for (int mi = 0; mi < 2; ++mi)
#pragma unroll
            for (int i = 0; i < 4; ++i) scpart[w][mi * 16 + q * 4 + i] = sr[mi][i];
    }
    __syncthreads();

    // wave-parallel softmax over the 32 scores (lanes 0..31 of wave 0; 32..63
    // replicate — shfl_xor with off<32 stays within each 32-lane half).
    if (t < 64) {
        int m = t & 31;
        float v = scpart[0][m] + scpart[1][m] + scpart[2][m] + scpart[3][m];
        float mx = v;
#pragma unroll
        for (int off = 1; off < 32; off <<= 1) mx = fmaxf(mx, __shfl_xor(mx, off));
        float e = __expf(v - mx);
        float sum = e;
#pragma unroll
        for (int off = 1; off < 32; off <<= 1) sum += __shfl_xor(sum, off);
        if (t < 32) attn[m] = e * __builtin_amdgcn_rcpf(sum);
    }
    __syncthreads();

    int h0 = t * 2;
    float p0 = 0.f, p1 = 0.f;
#pragma unroll
    for (int m = 0; m < 32; ++m) {
        float am = attn[m];
        p0 += am * bf2f(Xb[m][h0]);
        p1 += am * bf2f(Xb[m][h0 + 1]);
    }
    size_t r = (size_t)bid;
    ixf[r * H + h0] = p0;
    ixf[r * H + h0 + 1] = p1;
    ixb[r * H + h0] = f2bf(p0);
    ixb[r * H + h0 + 1] = f2bf(p1);
}

// ---------------------------------------------------------------------------
// ipre: i_pre[r,g] = sum_h i_x[r,h] * Wi[g,h] + bl[g]   (r < 1016)
// grid (64, 4): block = 16 rows x 128 g; wave = 16 rows x 32 g. No LDS.
// ---------------------------------------------------------------------------
__global__ __launch_bounds__(256) void ipre_kernel(
        const unsigned short* __restrict__ ixb, const unsigned short* __restrict__ WiS,
        const float* __restrict__ bl, float* __restrict__ ipre) {
    int row16 = blockIdx.x * 16;
    int t = threadIdx.x, w = t >> 6, lane = t & 63, q = lane >> 4, c16 = lane & 15;
    int c0 = blockIdx.y * 8 + w * 2;

    v4f acc0 = {0.f, 0.f, 0.f, 0.f};
    v4f acc1 = {0.f, 0.f, 0.f, 0.f};
    const unsigned short* arow = ixb + (size_t)(row16 + c16) * H + q * 8;
#pragma unroll
    for (int ks = 0; ks < 16; ++ks) {
        v8bf a = load_bf8(arow + ks * 32);
        acc0 = __builtin_amdgcn_mfma_f32_16x16x32_bf16(
            a, load_bf8(WiS + (size_t)(c0 * 16 + ks) * 512 + lane * 8), acc0, 0, 0, 0);
        acc1 = __builtin_amdgcn_mfma_f32_16x16x32_bf16(
            a, load_bf8(WiS + (size_t)((c0 + 1) * 16 + ks) * 512 + lane * 8), acc1, 0, 0, 0);
    }
#pragma unroll
    for (int cc = 0; cc < 2; ++cc) {
        int g = (c0 + cc) * 16 + c16;
        float blv = bl[g];
        v4f a = cc ? acc1 : acc0;
#pragma unroll
        for (int i = 0; i < 4; ++i) {
            int row = row16 + q * 4 + i;
            if (row < 1016) ipre[(size_t)row * H + g] = a[i] + blv;
        }
    }
}

// ---------------------------------------------------------------------------
// main: out[b,0]=y[b,0]; s>=1: pre = y@Wy^T + i_pre, out = y + i_x*sigmoid(pre)
// One block per (b, s, half): 32 rows x 512 cols.  wave = 32 rows x 128 cols,
// acc 2x8.  LDS 37.4 KB -> 4 blocks/CU (16 waves/CU) under 128-VGPR cap.
// ---------------------------------------------------------------------------
__global__ __launch_bounds__(256, 4) void main_kernel(
        const float* __restrict__ y, const unsigned short* __restrict__ WyS,
        const float* __restrict__ ixf, const float* __restrict__ ipre,
        float* __restrict__ out) {
    int half = blockIdx.x & 1;
    int s = blockIdx.x >> 1;           // 0..127
    int b = blockIdx.y;
    int t = threadIdx.x;
    size_t base  = (size_t)(b * SEQ + s) * 64 * H;
    size_t rbase = base + (size_t)half * 32 * H;   // this half's 32 rows

    if (s == 0) {
        const float4* y4 = reinterpret_cast<const float4*>(y + rbase);
        float4* o4 = reinterpret_cast<float4*>(out + rbase);
#pragma unroll
        for (int i = 0; i < 16; ++i) o4[t + i * 256] = y4[t + i * 256];
        return;
    }

    __shared__ __align__(16) unsigned short Yb[32][520];
    __shared__ float ip_s[512];
    __shared__ float ix_s[512];

    int r = b * 127 + (s - 1);
    const float4* y4 = reinterpret_cast<const float4*>(y + rbase);
#pragma unroll
    for (int i = 0; i < 16; ++i) {
        int idx4 = t + i * 256;
        float4 v = y4[idx4];
        int e = idx4 * 4, n = e >> 9, h = e & 511;
        ushort4 o;
        o.x = f2bf(v.x); o.y = f2bf(v.y); o.z = f2bf(v.z); o.w = f2bf(v.w);
        *reinterpret_cast<ushort4*>(&Yb[n][h]) = o;
    }
    ip_s[t]       = ipre[(size_t)r * H + t];
    ip_s[t + 256] = ipre[(size_t)r * H + t + 256];
    ix_s[t]       = ixf[(size_t)r * H + t];
    ix_s[t + 256] = ixf[(size_t)r * H + t + 256];
    __syncthreads();

    int w = t >> 6, lane = t & 63, q = lane >> 4, c16 = lane & 15;

    v4f acc[2][8];
#pragma unroll
    for (int rt = 0; rt < 2; ++rt)
#pragma unroll
        for (int ci = 0; ci < 8; ++ci) acc[rt][ci] = (v4f){0.f, 0.f, 0.f, 0.f};

    const unsigned short* Bb = WyS + (size_t)(w * 8 * 16) * 512 + lane * 8;

#pragma unroll
    for (int ks = 0; ks < 16; ++ks) {
        v8bf a0 = load_bf8(&Yb[c16][ks * 32 + q * 8]);
        v8bf a1 = load_bf8(&Yb[16 + c16][ks * 32 + q * 8]);
#pragma unroll
        for (int ci = 0; ci < 8; ++ci) {
            v8bf bb = load_bf8(Bb + (size_t)(ci * 16 + ks) * 512);
            acc[0][ci] = __builtin_amdgcn_mfma_f32_16x16x32_bf16(a0, bb, acc[0][ci], 0, 0, 0);
            acc[1][ci] = __builtin_amdgcn_mfma_f32_16x16x32_bf16(a1, bb, acc[1][ci], 0, 0, 0);
        }
    }

#pragma unroll
    for (int ci = 0; ci < 8; ++ci) {
        int g = (w * 8 + ci) * 16 + c16;
        float ip = ip_s[g];
        float ixv = ix_s[g];
#pragma unroll
        for (int rt = 0; rt < 2; ++rt)
#pragma unroll
            for (int i = 0; i < 4; ++i) {
                int nl = rt * 16 + q * 4 + i;      // local row 0..31
                float pre = acc[rt][ci][i] + ip;
                float gate = fast_sigmoid(pre);
                out[rbase + (size_t)nl * H + g] = bf2f(Yb[nl][g]) + ixv * gate;
            }
    }
}

// ---------------------------------------------------------------------------
extern "C" void kernel_launch(void* const* d_in, const int* in_sizes, int n_in,
                              void* d_out, int out_size, void* d_ws, size_t ws_size,
                              hipStream_t stream) {
    const float* x   = (const float*)d_in[0];
    const float* y   = (const float*)d_in[1];
    const float* Wa1 = (const float*)d_in[2];
    const float* ba1 = (const float*)d_in[3];
    const float* wa2 = (const float*)d_in[4];
    const float* Wl  = (const float*)d_in[5];
    const float* bl  = (const float*)d_in[6];
    float* out = (float*)d_out;

    char* ws = (char*)d_ws;
    unsigned short* WyS  = (unsigned short*)(ws);                     // 512 KB
    unsigned short* WiS  = (unsigned short*)(ws + 524288);            // 512 KB
    unsigned short* WaS  = (unsigned short*)(ws + 1048576);           // 512 KB
    float*          ixf  = (float*)(ws + 1572864);                    // 2 MB (1024 rows)
    unsigned short* ixb  = (unsigned short*)(ws + 3670016);           // 1 MB (1024 rows)
    float*          ipre = (float*)(ws + 4718592);                    // 2 MB (1024 rows)

    hipLaunchKernelGGL(prep_kernel, dim3(384), dim3(256), 0, stream, Wa1, Wl, WyS, WiS, WaS);
    hipLaunchKernelGGL(attn_pool_kernel, dim3(1016), dim3(256), 0, stream,
                       x, WaS, ba1, wa2, ixf, ixb);
    hipLaunchKernelGGL(ipre_kernel, dim3(64, 4), dim3(256), 0, stream, ixb, WiS, bl, ipre);
    hipLaunchKernelGGL(main_kernel, dim3(256, 8), dim3(256), 0, stream,
                       y, WyS, ixf, ipre, out);
}